// Round 16
// baseline (82.395 us; speedup 1.0000x reference)
//
#include <hip/hip_runtime.h>
#include <stdint.h>

// HypergraphConv: B=8, N=2048, E=1024, Fin=Fout=256, fp32 in/out.
// out = relu( Dv^-1 * H @ (De^-1 * (H^T @ (x@W))) )
// R16: degrees computed IN-GEMM via all-ones MFMA operand (De inside gemm2,
// Dv inside gemm3) -- DePart/DvInv and all prep reductions deleted. prep is a
// pure streaming fp32->bf16 convert fused with gemm1. gemm2: in-kernel B
// transpose (R15). gemm3: 3-buf depth-2 counted-vmcnt (R15).

typedef __bf16 bf16x8 __attribute__((ext_vector_type(8)));
typedef float f32x4 __attribute__((ext_vector_type(4)));

__device__ __forceinline__ uint16_t f2b(float f) {
  __bf16 h = (__bf16)f;
  return __builtin_bit_cast(uint16_t, h);
}

__device__ __forceinline__ f32x4 mfma16(bf16x8 a, bf16x8 b, f32x4 c) {
  return __builtin_amdgcn_mfma_f32_16x16x32_bf16(a, b, c, 0, 0, 0);
}

__device__ __forceinline__ bf16x8 ones8() {
  __bf16 one = (__bf16)1.0f;
  bf16x8 v = {one, one, one, one, one, one, one, one};
  return v;
}

// async global->LDS, 16B/lane; LDS dest = uniform base + lane*16
__device__ __forceinline__ void gload16(const void* src, void* dst) {
  __builtin_amdgcn_global_load_lds(
      (const __attribute__((address_space(1))) void*)src,
      (__attribute__((address_space(3))) void*)dst, 16, 0, 0);
}

#define PIPE_WAIT4() do { \
    asm volatile("s_waitcnt vmcnt(4)" ::: "memory"); \
    __builtin_amdgcn_s_barrier(); \
    __builtin_amdgcn_sched_barrier(0); \
  } while (0)
#define PIPE_WAIT0() do { \
    asm volatile("s_waitcnt vmcnt(0)" ::: "memory"); \
    __builtin_amdgcn_s_barrier(); \
    __builtin_amdgcn_sched_barrier(0); \
  } while (0)

// ---- prep_w: Wt[f][k] = bf16(W[k][f]), 64x64 LDS transpose tiles ----
__global__ __launch_bounds__(256) void k_prep_w(const float* __restrict__ W,
    uint16_t* __restrict__ Wt) {
  __shared__ __align__(16) uint16_t T[64 * 68];
  const int k0 = blockIdx.x * 64, f0 = blockIdx.y * 64;
  const int t = threadIdx.x;
  const int r0 = (t >> 4) * 4, cc = (t & 15) * 4;
  float vv[4][4];
  #pragma unroll
  for (int i = 0; i < 4; ++i) {
    float4 q = *(const float4*)(W + (size_t)(k0 + r0 + i) * 256 + f0 + cc);
    vv[i][0] = q.x; vv[i][1] = q.y; vv[i][2] = q.z; vv[i][3] = q.w;
  }
  #pragma unroll
  for (int j = 0; j < 4; ++j) {
    union { uint16_t s[4]; uint2 u; } p;
    #pragma unroll
    for (int i = 0; i < 4; ++i) p.s[i] = f2b(vv[i][j]);
    *(uint2*)&T[(cc + j) * 68 + r0] = p.u;
  }
  __syncthreads();
  const int er = t >> 2, c2 = (t & 3) * 16;
  union { uint16_t s[16]; uint4 q[2]; } o;
  #pragma unroll
  for (int m = 0; m < 4; ++m)
    *(uint2*)&o.s[m * 4] = *(const uint2*)&T[er * 68 + c2 + m * 4];
  uint16_t* dst = Wt + (size_t)(f0 + er) * 256 + k0 + c2;
  *(uint4*)dst = o.q[0];
  *(uint4*)(dst + 8) = o.q[1];
}

// ---- phase1: blocks [0,1024) = pure convert H->Hb; [1024,2048) = gemm1 ----
__global__ __launch_bounds__(256) void k_phase1(const float* __restrict__ H,
    const float* __restrict__ X, const uint16_t* __restrict__ Wt,
    uint16_t* __restrict__ Hb, uint16_t* __restrict__ XWt) {
  __shared__ __align__(16) unsigned char smem[17408];
  const int lin = blockIdx.x;
  const int t = threadIdx.x, lane = t & 63, wave = t >> 6;

  if (lin < 1024) {
    // ======== prep: pure streaming convert, 16 rows x 1024 e ========
    const int nb = lin & 127, b = lin >> 7;
    const int n0 = nb * 16;
    const float* Hrow = H + ((size_t)b * 2048 + n0) * 1024 + t * 4;
    uint16_t* HbRow = Hb + ((size_t)b * 2048 + n0) * 1024 + t * 4;
    #pragma unroll
    for (int g = 0; g < 2; ++g) {
      float4 q[8];
      #pragma unroll
      for (int i = 0; i < 8; ++i)
        q[i] = *(const float4*)(Hrow + (size_t)(g * 8 + i) * 1024);
      #pragma unroll
      for (int i = 0; i < 8; ++i) {
        union { uint16_t s[4]; uint2 u; } p;
        p.s[0] = f2b(q[i].x); p.s[1] = f2b(q[i].y);
        p.s[2] = f2b(q[i].z); p.s[3] = f2b(q[i].w);
        *(uint2*)(HbRow + (size_t)(g * 8 + i) * 1024) = p.u;
      }
    }
  } else {
    // ======== GEMM1: tile 64f x 64n, K=256, BK=64, single-buffered ========
    uint16_t* As = (uint16_t*)smem;            // [64][64]
    uint16_t* Bs = (uint16_t*)(smem + 8192);   // [64][72]
    const int l1 = lin - 1024;
    const int n0 = (l1 & 31) * 64, f0 = ((l1 >> 5) & 3) * 64, b = l1 >> 7;
    const int l15 = lane & 15, lq = lane >> 4;
    const int rlane = lane >> 3;
    const int srcswz = ((lane & 7) ^ rlane) << 3;
    const uint16_t* Ag = Wt + (size_t)f0 * 256;
    const int br = t >> 2, kc = (t & 3) * 16;
    const float* Xg = X + ((size_t)b * 2048 + n0 + br) * 256 + kc;
    f32x4 acc[2][2] = {};
    for (int kt = 0; kt < 4; ++kt) {
      if (kt) __syncthreads();
      const int k0 = kt * 64;
      #pragma unroll
      for (int i = 0; i < 2; ++i) {
        const int r = wave * 16 + i * 8;
        gload16(Ag + (size_t)(r + rlane) * 256 + k0 + srcswz, As + r * 64);
      }
      {
        float4 RX[4];
        const float* s = Xg + k0;
        #pragma unroll
        for (int q = 0; q < 4; ++q) RX[q] = *(const float4*)(s + q * 4);
        uint16_t* d = Bs + br * 72 + kc;
        const float* f = (const float*)RX;
        #pragma unroll
        for (int q = 0; q < 2; ++q) {
          union { uint16_t s[8]; uint4 u; } p;
          #pragma unroll
          for (int j = 0; j < 8; ++j) p.s[j] = f2b(f[q * 8 + j]);
          *(uint4*)(d + q * 8) = p.u;
        }
      }
      __syncthreads();
      #pragma unroll
      for (int h = 0; h < 2; ++h) {
        bf16x8 af[2], bf[2];
        #pragma unroll
        for (int i = 0; i < 2; ++i) {
          const int r = (wave >> 1) * 32 + i * 16 + l15;
          af[i] = *(const bf16x8*)(As + r * 64 + ((((h << 2) | lq) ^ (r & 7)) << 3));
        }
        #pragma unroll
        for (int j = 0; j < 2; ++j) {
          const int r = (wave & 1) * 32 + j * 16 + l15;
          bf[j] = *(const bf16x8*)(Bs + r * 72 + h * 32 + lq * 8);
        }
        #pragma unroll
        for (int i = 0; i < 2; ++i)
          #pragma unroll
          for (int j = 0; j < 2; ++j)
            acc[i][j] = mfma16(af[i], bf[j], acc[i][j]);
      }
    }
    #pragma unroll
    for (int i = 0; i < 2; ++i) {
      const int fr = f0 + (wave >> 1) * 32 + i * 16 + lq * 4;
      #pragma unroll
      for (int j = 0; j < 2; ++j) {
        const int col = n0 + (wave & 1) * 32 + j * 16 + l15;
        #pragma unroll
        for (int reg = 0; reg < 4; ++reg)
          XWt[((size_t)b * 256 + fr + reg) * 2048 + col] = f2b(acc[i][j][reg]);
      }
    }
  }
}

// ---- GEMM2: Yt[b][f][e] = bf16( DeInv * sum_n XWt[f][n]*Hb[n][e] ) ----
// tile 64f x 64e, K=2048 (NT=32). grid (16, 4, 8). A: gload_lds 3-buf.
// B: in-kernel transpose from Hb. De computed in-GEMM: mfma(ONES, B).
__global__ __launch_bounds__(256) void k_gemm2(const uint16_t* __restrict__ Hb,
    const uint16_t* __restrict__ XWt, uint16_t* __restrict__ Yt) {
  __shared__ __align__(16) uint16_t As[3][64 * 64];   // 24KB
  __shared__ __align__(16) uint16_t Bsm[2][64 * 72];  // 18KB, [e][n] pad 72
  const int e0 = blockIdx.x * 64, f0 = blockIdx.y * 64, b = blockIdx.z;
  const int t = threadIdx.x, lane = t & 63, wave = t >> 6;
  const int l15 = lane & 15, lq = lane >> 4;
  const int rlane = lane >> 3;
  const int srcswz = ((lane & 7) ^ rlane) << 3;
  const bf16x8 ONES = ones8();
  const uint16_t* Ag = XWt + ((size_t)b * 256 + f0) * 2048;
  const int br0 = (t >> 4) * 4;   // 4 consecutive n within K-tile
  const int bcc = (t & 15) * 4;   // 4 consecutive e
  const uint16_t* Bgb = Hb + (size_t)b * 2048 * 1024 + e0 + bcc;
  auto stageA = [&](uint16_t* Ad, int kt) {  // 2 gload_lds / wave
    const int k0 = kt * 64;
    #pragma unroll
    for (int i = 0; i < 2; ++i) {
      const int r = wave * 16 + i * 8;
      gload16(Ag + (size_t)(r + rlane) * 2048 + k0 + srcswz, Ad + r * 64);
    }
  };
  auto loadB = [&](uint2* R, int kt) {  // 4 uint2 loads (8B, 128B-coalesced)
    const uint16_t* s = Bgb + (size_t)(kt * 64 + br0) * 1024;
    #pragma unroll
    for (int i = 0; i < 4; ++i) R[i] = *(const uint2*)(s + (size_t)i * 1024);
  };
  auto writeB = [&](uint16_t* Bd, const uint2* R) {  // 4 ds_write_b64, transposed
    #pragma unroll
    for (int j = 0; j < 4; ++j) {
      union { uint16_t s[4]; uint2 u; } p;
      #pragma unroll
      for (int i = 0; i < 4; ++i) p.s[i] = ((const uint16_t*)&R[i])[j];
      *(uint2*)&Bd[(bcc + j) * 72 + br0] = p.u;
    }
  };
  f32x4 acc[2][2] = {};
  f32x4 acc_de[2] = {};
  auto compute = [&](const uint16_t* Ad, const uint16_t* Bd) {
    #pragma unroll
    for (int h = 0; h < 2; ++h) {
      bf16x8 af[2], bf[2];
      #pragma unroll
      for (int i = 0; i < 2; ++i) {
        const int r = (wave >> 1) * 32 + i * 16 + l15;
        af[i] = *(const bf16x8*)(Ad + r * 64 + ((((h << 2) | lq) ^ (r & 7)) << 3));
      }
      #pragma unroll
      for (int j = 0; j < 2; ++j) {
        const int r = (wave & 1) * 32 + j * 16 + l15;
        bf[j] = *(const bf16x8*)(Bd + r * 72 + h * 32 + lq * 8);
      }
      #pragma unroll
      for (int i = 0; i < 2; ++i)
        #pragma unroll
        for (int j = 0; j < 2; ++j)
          acc[i][j] = mfma16(af[i], bf[j], acc[i][j]);
      #pragma unroll
      for (int j = 0; j < 2; ++j)
        acc_de[j] = mfma16(ONES, bf[j], acc_de[j]);  // col-sums -> De
    }
  };
  uint2 RB0[4], RB1[4];
  // prologue
  loadB(RB0, 0);
  stageA(As[0], 0);
  stageA(As[1], 1);
  asm volatile("s_waitcnt vmcnt(4)" ::: "memory");   // RB0 done
  writeB(Bsm[0], RB0);
  loadB(RB1, 1);
  asm volatile("s_waitcnt vmcnt(6) lgkmcnt(0)" ::: "memory");  // A0 done, LDS drained
  __builtin_amdgcn_s_barrier();
  __builtin_amdgcn_sched_barrier(0);
  const int NT = 32;
  uint16_t *cA = As[0], *nA = As[1], *fA = As[2];
  #define G2_STEP(KT, RBH, RBF, BSC, BSN)                                    \
    do {                                                                     \
      stageA(fA, (KT) + 2);                                                  \
      loadB(RBF, (KT) + 2);                                                  \
      compute(cA, BSC);                                                      \
      asm volatile("s_waitcnt vmcnt(6)" ::: "memory");                       \
      writeB(BSN, RBH);                                                      \
      asm volatile("s_waitcnt lgkmcnt(0)" ::: "memory");                     \
      __builtin_amdgcn_s_barrier();                                          \
      __builtin_amdgcn_sched_barrier(0);                                     \
      uint16_t* tp = cA; cA = nA; nA = fA; fA = tp;                          \
    } while (0)
  for (int kt = 0; kt < NT - 2; kt += 2) {
    G2_STEP(kt,     RB1, RB0, Bsm[0], Bsm[1]);
    G2_STEP(kt + 1, RB0, RB1, Bsm[1], Bsm[0]);
  }
  #undef G2_STEP
  // kt = 30: held RB1 = B(31); no more prefetch
  compute(cA, Bsm[0]);                                  // tile 30
  asm volatile("s_waitcnt vmcnt(0)" ::: "memory");      // A(31) landed
  writeB(Bsm[1], RB1);
  asm volatile("s_waitcnt lgkmcnt(0)" ::: "memory");
  __builtin_amdgcn_s_barrier();
  __builtin_amdgcn_sched_barrier(0);
  compute(nA, Bsm[1]);                                  // tile 31
  #pragma unroll
  for (int i = 0; i < 2; ++i) {
    const int fr = f0 + (wave >> 1) * 32 + i * 16 + lq * 4;
    #pragma unroll
    for (int j = 0; j < 2; ++j) {
      const int el = (wave & 1) * 32 + j * 16 + l15;
      const float sc = 1.f / (acc_de[j][0] + 1e-9f);   // per-lane De (all regs equal)
      uint16_t* dst = Yt + ((size_t)b * 256 + fr) * 1024 + e0 + el;
      #pragma unroll
      for (int reg = 0; reg < 4; ++reg)
        dst[(size_t)reg * 1024] = f2b(acc[i][j][reg] * sc);
    }
  }
}

// ---- GEMM3: out[b][n][f] = relu( DvInv[b,n] * sum_e Hb[n][e]*Yt[f][e] ) ----
// tile 64n x 64f, K=1024 (NT=16). grid (32, 4, 8). 3-buf depth-2, vmcnt(4).
// Dv computed in-GEMM: mfma(A, ONES) row-sums.
__global__ __launch_bounds__(256) void k_gemm3(const uint16_t* __restrict__ Hb,
    const uint16_t* __restrict__ Yt, float* __restrict__ out) {
  __shared__ __align__(16) uint16_t As[3][64 * 64];
  __shared__ __align__(16) uint16_t Bs[3][64 * 64];
  const int n0 = blockIdx.x * 64, f0 = blockIdx.y * 64, b = blockIdx.z;
  const int t = threadIdx.x, lane = t & 63, wave = t >> 6;
  const int l15 = lane & 15, lq = lane >> 4;
  const int rlane = lane >> 3;
  const int srcswz = ((lane & 7) ^ rlane) << 3;
  const bf16x8 ONES = ones8();
  const uint16_t* Ag = Hb + ((size_t)b * 2048 + n0) * 1024;
  const uint16_t* Bg = Yt + ((size_t)b * 256 + f0) * 1024;
  auto stage = [&](uint16_t* Ad, uint16_t* Bd, int kt) {  // 4 VMEM / wave
    const int k0 = kt * 64;
    #pragma unroll
    for (int i = 0; i < 2; ++i) {
      const int r = wave * 16 + i * 8;
      gload16(Ag + (size_t)(r + rlane) * 1024 + k0 + srcswz, Ad + r * 64);
      gload16(Bg + (size_t)(r + rlane) * 1024 + k0 + srcswz, Bd + r * 64);
    }
  };
  f32x4 acc[2][2] = {};
  f32x4 acc_dv[2] = {};
  auto compute = [&](const uint16_t* Ad, const uint16_t* Bd) {
    #pragma unroll
    for (int h = 0; h < 2; ++h) {
      bf16x8 af[2], bf[2];
      #pragma unroll
      for (int i = 0; i < 2; ++i) {
        const int r = (wave >> 1) * 32 + i * 16 + l15;
        af[i] = *(const bf16x8*)(Ad + r * 64 + ((((h << 2) | lq) ^ (r & 7)) << 3));
      }
      #pragma unroll
      for (int j = 0; j < 2; ++j) {
        const int r = (wave & 1) * 32 + j * 16 + l15;
        bf[j] = *(const bf16x8*)(Bd + r * 64 + ((((h << 2) | lq) ^ (r & 7)) << 3));
      }
      #pragma unroll
      for (int i = 0; i < 2; ++i)
        #pragma unroll
        for (int j = 0; j < 2; ++j)
          acc[i][j] = mfma16(af[i], bf[j], acc[i][j]);
      #pragma unroll
      for (int i = 0; i < 2; ++i)
        acc_dv[i] = mfma16(af[i], ONES, acc_dv[i]);  // row-sums -> Dv
    }
  };
  stage(As[0], Bs[0], 0);
  stage(As[1], Bs[1], 1);
  __syncthreads();
  const int NT = 16;
  uint16_t *cA = As[0], *nA = As[1], *fA = As[2];
  uint16_t *cB = Bs[0], *nB = Bs[1], *fB = Bs[2];
  for (int kt = 0; kt < NT - 2; ++kt) {
    stage(fA, fB, kt + 2);
    compute(cA, cB);
    PIPE_WAIT4();
    uint16_t* t1 = cA; cA = nA; nA = fA; fA = t1;
    uint16_t* t2 = cB; cB = nB; nB = fB; fB = t2;
  }
  compute(cA, cB);   // tile NT-2
  PIPE_WAIT0();
  compute(nA, nB);   // tile NT-1
  #pragma unroll
  for (int i = 0; i < 2; ++i) {
    const int nl = (wave >> 1) * 32 + i * 16 + lq * 4;
    #pragma unroll
    for (int reg = 0; reg < 4; ++reg) {
      const int row = n0 + nl + reg;
      const float sc = 1.f / (acc_dv[i][reg] + 1e-9f);  // per-lane Dv (all cols equal)
      #pragma unroll
      for (int j = 0; j < 2; ++j) {
        const int col = f0 + (wave & 1) * 32 + j * 16 + l15;
        const float v = acc[i][j][reg] * sc;
        out[((size_t)b * 2048 + row) * 256 + col] = v > 0.f ? v : 0.f;
      }
    }
  }
}

extern "C" void kernel_launch(void* const* d_in, const int* in_sizes, int n_in,
                              void* d_out, int out_size, void* d_ws, size_t ws_size,
                              hipStream_t stream) {
  (void)in_sizes; (void)n_in; (void)out_size;
  const float* x = (const float*)d_in[0];   // [8,2048,256]
  const float* H = (const float*)d_in[1];   // [8,2048,1024]
  const float* W = (const float*)d_in[2];   // [256,256]
  float* out = (float*)d_out;               // [8,2048,256]

  // workspace layout (bytes):
  //   Hb     bf16 [8,2048,1024] : 0        .. 33554432
  //   XWt    bf16 [8,256,2048]  : 33554432 .. 41943040
  //   Yt     bf16 [8,256,1024]  : 41943040 .. 46137344
  //   Wt     bf16 [256,256]     : 46137344 .. 46268416
  if (ws_size < 46268416) return;
  char* ws = (char*)d_ws;
  uint16_t* Hb  = (uint16_t*)(ws);
  uint16_t* XWt = (uint16_t*)(ws + 33554432);
  uint16_t* Yt  = (uint16_t*)(ws + 41943040);
  uint16_t* Wt  = (uint16_t*)(ws + 46137344);

  k_prep_w<<<dim3(4, 4),     256, 0, stream>>>(W, Wt);
  k_phase1<<<dim3(2048),     256, 0, stream>>>(H, x, Wt, Hb, XWt);
  k_gemm2 <<<dim3(16, 4, 8), 256, 0, stream>>>(Hb, XWt, Yt);
  k_gemm3 <<<dim3(32, 4, 8), 256, 0, stream>>>(Hb, Yt, out);
}

// Round 17
// 76.372 us; speedup vs baseline: 1.0789x; 1.0789x over previous
//
#include <hip/hip_runtime.h>
#include <stdint.h>

// HypergraphConv: B=8, N=2048, E=1024, Fin=Fout=256, fp32 in/out.
// out = relu( Dv^-1 * H @ (De^-1 * (H^T @ (x@W))) )
// R17 = R12 verbatim (session-best measured: 76.6us).
// phase1 (fused prep_h + gemm1) is at the d_in mixed-stream plateau (~3TB/s,
// proven structure-insensitive across R12-R16); gemm2/gemm3 are the 64x64
// 3-buffer counted-vmcnt pipelines (best of 4 structural variants).

typedef __bf16 bf16x8 __attribute__((ext_vector_type(8)));
typedef float f32x4 __attribute__((ext_vector_type(4)));

#define PADK 72  // padded row stride (elems) for f32-reg-staged tiles

__device__ __forceinline__ uint16_t f2b(float f) {
  __bf16 h = (__bf16)f;
  return __builtin_bit_cast(uint16_t, h);
}

__device__ __forceinline__ f32x4 mfma16(bf16x8 a, bf16x8 b, f32x4 c) {
  return __builtin_amdgcn_mfma_f32_16x16x32_bf16(a, b, c, 0, 0, 0);
}

// async global->LDS, 16B/lane; LDS dest = uniform base + lane*16
__device__ __forceinline__ void gload16(const void* src, void* dst) {
  __builtin_amdgcn_global_load_lds(
      (const __attribute__((address_space(1))) void*)src,
      (__attribute__((address_space(3))) void*)dst, 16, 0, 0);
}

#define PIPE_WAIT4() do { \
    asm volatile("s_waitcnt vmcnt(4)" ::: "memory"); \
    __builtin_amdgcn_s_barrier(); \
    __builtin_amdgcn_sched_barrier(0); \
  } while (0)
#define PIPE_WAIT0() do { \
    asm volatile("s_waitcnt vmcnt(0)" ::: "memory"); \
    __builtin_amdgcn_s_barrier(); \
    __builtin_amdgcn_sched_barrier(0); \
  } while (0)

// ---- prep_w: Wt[f][k] = bf16(W[k][f]), 64x64 LDS transpose tiles ----
__global__ __launch_bounds__(256) void k_prep_w(const float* __restrict__ W,
    uint16_t* __restrict__ Wt) {
  __shared__ __align__(16) uint16_t T[64 * 68];
  const int k0 = blockIdx.x * 64, f0 = blockIdx.y * 64;
  const int t = threadIdx.x;
  const int r0 = (t >> 4) * 4, cc = (t & 15) * 4;
  float vv[4][4];
  #pragma unroll
  for (int i = 0; i < 4; ++i) {
    float4 q = *(const float4*)(W + (size_t)(k0 + r0 + i) * 256 + f0 + cc);
    vv[i][0] = q.x; vv[i][1] = q.y; vv[i][2] = q.z; vv[i][3] = q.w;
  }
  #pragma unroll
  for (int j = 0; j < 4; ++j) {
    union { uint16_t s[4]; uint2 u; } p;
    #pragma unroll
    for (int i = 0; i < 4; ++i) p.s[i] = f2b(vv[i][j]);
    *(uint2*)&T[(cc + j) * 68 + r0] = p.u;
  }
  __syncthreads();
  const int er = t >> 2, c2 = (t & 3) * 16;
  union { uint16_t s[16]; uint4 q[2]; } o;
  #pragma unroll
  for (int m = 0; m < 4; ++m)
    *(uint2*)&o.s[m * 4] = *(const uint2*)&T[er * 68 + c2 + m * 4];
  uint16_t* dst = Wt + (size_t)(f0 + er) * 256 + k0 + c2;
  *(uint4*)dst = o.q[0];
  *(uint4*)(dst + 8) = o.q[1];
}

// ---- phase1: blocks [0,512) = gemm1 (XWt = (x@W)^T); [512,4608) = prep_h ----
// Shared-memory overlay: gemm1 uses 25600B (As 16384 + Bs 9216); prep uses
// 9728B (T 8704 + cs 1024). Static LDS = 25600B -> 6 blocks/CU.
__global__ __launch_bounds__(256) void k_phase1(const float* __restrict__ H,
    const float* __restrict__ X, const uint16_t* __restrict__ Wt,
    uint16_t* __restrict__ Hbt, uint16_t* __restrict__ Hb,
    float* __restrict__ DvPart, float* __restrict__ DePart,
    uint16_t* __restrict__ XWt) {
  __shared__ __align__(16) unsigned char smem[25600];
  const int lin = blockIdx.x;
  const int t = threadIdx.x, lane = t & 63, wave = t >> 6;

  if (lin < 512) {
    // ======== GEMM1: tile 128f x 64n, K=256, BK=64, single-buffered ========
    uint16_t* As = (uint16_t*)smem;            // [128][64]
    uint16_t* Bs = (uint16_t*)(smem + 16384);  // [64][PADK]
    const int n0 = (lin & 31) * 64, f0 = ((lin >> 5) & 1) * 128, b = lin >> 6;
    const int l15 = lane & 15, lq = lane >> 4;
    const int rlane = lane >> 3;
    const int srcswz = ((lane & 7) ^ rlane) << 3;
    const uint16_t* Ag = Wt + (size_t)f0 * 256;
    const int br = t >> 2, kc = (t & 3) * 16;
    const float* Xg = X + ((size_t)b * 2048 + n0 + br) * 256 + kc;
    f32x4 acc[4][2] = {};
    for (int kt = 0; kt < 4; ++kt) {
      if (kt) __syncthreads();
      const int k0 = kt * 64;
      #pragma unroll
      for (int i = 0; i < 4; ++i) {
        const int r = wave * 32 + i * 8;
        gload16(Ag + (size_t)(r + rlane) * 256 + k0 + srcswz, As + r * 64);
      }
      {
        float4 RX[4];
        const float* s = Xg + k0;
        #pragma unroll
        for (int q = 0; q < 4; ++q) RX[q] = *(const float4*)(s + q * 4);
        uint16_t* d = Bs + br * PADK + kc;
        const float* f = (const float*)RX;
        #pragma unroll
        for (int q = 0; q < 2; ++q) {
          union { uint16_t s[8]; uint4 u; } p;
          #pragma unroll
          for (int j = 0; j < 8; ++j) p.s[j] = f2b(f[q * 8 + j]);
          *(uint4*)(d + q * 8) = p.u;
        }
      }
      __syncthreads();
      #pragma unroll
      for (int h = 0; h < 2; ++h) {
        bf16x8 af[4], bf[2];
        #pragma unroll
        for (int i = 0; i < 4; ++i) {
          const int r = (wave >> 1) * 64 + i * 16 + l15;
          af[i] = *(const bf16x8*)(As + r * 64 + ((((h << 2) | lq) ^ (r & 7)) << 3));
        }
        #pragma unroll
        for (int j = 0; j < 2; ++j) {
          const int r = (wave & 1) * 32 + j * 16 + l15;
          bf[j] = *(const bf16x8*)(Bs + r * PADK + h * 32 + lq * 8);
        }
        #pragma unroll
        for (int i = 0; i < 4; ++i)
          #pragma unroll
          for (int j = 0; j < 2; ++j)
            acc[i][j] = mfma16(af[i], bf[j], acc[i][j]);
      }
    }
    #pragma unroll
    for (int i = 0; i < 4; ++i) {
      const int fr = f0 + (wave >> 1) * 64 + i * 16 + lq * 4;
      #pragma unroll
      for (int j = 0; j < 2; ++j) {
        const int col = n0 + (wave & 1) * 32 + j * 16 + l15;
        #pragma unroll
        for (int reg = 0; reg < 4; ++reg)
          XWt[((size_t)b * 256 + fr + reg) * 2048 + col] = f2b(acc[i][j][reg]);
      }
    }
  } else {
    // ======== prep_h: one 64n x 64e tile, ONE barrier ========
    uint16_t* T = (uint16_t*)smem;          // [64][68]
    float* cs = (float*)(smem + 8704);      // [4][64]
    const int l2 = lin - 512;
    const int n0 = (l2 & 31) * 64, e0 = ((l2 >> 5) & 15) * 64, b = l2 >> 9;
    const int r0 = (t >> 4) * 4;
    const int cc = (t & 15) * 4;
    float vv[4][4];
    float dv[4];
    float de0 = 0.f, de1 = 0.f, de2 = 0.f, de3 = 0.f;
    #pragma unroll
    for (int i = 0; i < 4; ++i) {
      float4 q = *(const float4*)(H + ((size_t)b * 2048 + n0 + r0 + i) * 1024 + e0 + cc);
      vv[i][0] = q.x; vv[i][1] = q.y; vv[i][2] = q.z; vv[i][3] = q.w;
      float rs = (q.x + q.y) + (q.z + q.w);
      rs += __shfl_xor(rs, 1); rs += __shfl_xor(rs, 2);
      rs += __shfl_xor(rs, 4); rs += __shfl_xor(rs, 8);
      dv[i] = rs;
      de0 += q.x; de1 += q.y; de2 += q.z; de3 += q.w;
    }
    #pragma unroll
    for (int i = 0; i < 4; ++i) {
      union { uint16_t s[4]; uint2 u; } p;
      #pragma unroll
      for (int j = 0; j < 4; ++j) p.s[j] = f2b(vv[i][j]);
      *(uint2*)(Hb + ((size_t)b * 2048 + n0 + r0 + i) * 1024 + e0 + cc) = p.u;
    }
    #pragma unroll
    for (int j = 0; j < 4; ++j) {
      union { uint16_t s[4]; uint2 u; } p;
      #pragma unroll
      for (int i = 0; i < 4; ++i) p.s[i] = f2b(vv[i][j]);
      *(uint2*)&T[(cc + j) * 68 + r0] = p.u;
    }
    de0 += __shfl_xor(de0, 16); de0 += __shfl_xor(de0, 32);
    de1 += __shfl_xor(de1, 16); de1 += __shfl_xor(de1, 32);
    de2 += __shfl_xor(de2, 16); de2 += __shfl_xor(de2, 32);
    de3 += __shfl_xor(de3, 16); de3 += __shfl_xor(de3, 32);
    if (lane < 16) *(float4*)&cs[wave * 64 + cc] = make_float4(de0, de1, de2, de3);
    if ((lane & 15) == 0) {
      #pragma unroll
      for (int i = 0; i < 4; ++i)
        DvPart[((size_t)b * 2048 + n0 + r0 + i) * 16 + ((l2 >> 5) & 15)] = dv[i];
    }
    __syncthreads();
    const int er = t >> 2, c2 = (t & 3) * 16;
    union { uint16_t s[16]; uint4 q[2]; } o;
    #pragma unroll
    for (int m = 0; m < 4; ++m)
      *(uint2*)&o.s[m * 4] = *(const uint2*)&T[er * 68 + c2 + m * 4];
    uint16_t* dst = Hbt + ((size_t)b * 1024 + e0 + er) * 2048 + n0 + c2;
    *(uint4*)dst = o.q[0];
    *(uint4*)(dst + 8) = o.q[1];
    if (t < 64) {
      float s = (cs[0 * 64 + t] + cs[1 * 64 + t]) + (cs[2 * 64 + t] + cs[3 * 64 + t]);
      DePart[((size_t)b * 1024 + e0 + t) * 32 + (l2 & 31)] = s;  // [b][e][32]
    }
  }
}

// ---- GEMM2: Yt[b][f][e] = bf16( DeInv[b,e] * sum_n XWt[f][n]*Hbt[e][n] ) ----
// tile 64f x 64e, K=2048 (NT=32). grid (16, 4, 8). depth-2 pipeline, vmcnt(4).
__global__ __launch_bounds__(256) void k_gemm2(const uint16_t* __restrict__ Hbt,
    const uint16_t* __restrict__ XWt, const float* __restrict__ DePart,
    uint16_t* __restrict__ Yt) {
  __shared__ __align__(16) uint16_t As[3][64 * 64];
  __shared__ __align__(16) uint16_t Bs[3][64 * 64];
  __shared__ float sde[64];
  const int e0 = blockIdx.x * 64, f0 = blockIdx.y * 64, b = blockIdx.z;
  const int t = threadIdx.x, lane = t & 63, wave = t >> 6;
  const int l15 = lane & 15, lq = lane >> 4;
  const int rlane = lane >> 3;
  const int srcswz = ((lane & 7) ^ rlane) << 3;
  const uint16_t* Ag = XWt + ((size_t)b * 256 + f0) * 2048;
  const uint16_t* Bg = Hbt + ((size_t)b * 1024 + e0) * 2048;
  auto stage = [&](uint16_t* Ad, uint16_t* Bd, int kt) {  // 4 VMEM instrs/wave
    const int k0 = kt * 64;
    #pragma unroll
    for (int i = 0; i < 2; ++i) {
      const int r = wave * 16 + i * 8;
      gload16(Ag + (size_t)(r + rlane) * 2048 + k0 + srcswz, Ad + r * 64);
      gload16(Bg + (size_t)(r + rlane) * 2048 + k0 + srcswz, Bd + r * 64);
    }
  };
  f32x4 acc[2][2] = {};
  auto compute = [&](const uint16_t* Ad, const uint16_t* Bd) {
    #pragma unroll
    for (int h = 0; h < 2; ++h) {
      bf16x8 af[2], bf[2];
      #pragma unroll
      for (int i = 0; i < 2; ++i) {
        const int r = (wave >> 1) * 32 + i * 16 + l15;
        af[i] = *(const bf16x8*)(Ad + r * 64 + ((((h << 2) | lq) ^ (r & 7)) << 3));
      }
      #pragma unroll
      for (int j = 0; j < 2; ++j) {
        const int r = (wave & 1) * 32 + j * 16 + l15;
        bf[j] = *(const bf16x8*)(Bd + r * 64 + ((((h << 2) | lq) ^ (r & 7)) << 3));
      }
      #pragma unroll
      for (int i = 0; i < 2; ++i)
        #pragma unroll
        for (int j = 0; j < 2; ++j)
          acc[i][j] = mfma16(af[i], bf[j], acc[i][j]);
    }
  };
  if (t < 64) {
    const float* p = DePart + ((size_t)b * 1024 + e0 + t) * 32;
    float4 a0 = *(const float4*)(p + 0),  a1 = *(const float4*)(p + 4);
    float4 a2 = *(const float4*)(p + 8),  a3 = *(const float4*)(p + 12);
    float4 a4 = *(const float4*)(p + 16), a5 = *(const float4*)(p + 20);
    float4 a6 = *(const float4*)(p + 24), a7 = *(const float4*)(p + 28);
    float s = (((a0.x + a0.y) + (a0.z + a0.w)) + ((a1.x + a1.y) + (a1.z + a1.w)))
            + (((a2.x + a2.y) + (a2.z + a2.w)) + ((a3.x + a3.y) + (a3.z + a3.w)))
            + ((((a4.x + a4.y) + (a4.z + a4.w)) + ((a5.x + a5.y) + (a5.z + a5.w)))
            + (((a6.x + a6.y) + (a6.z + a6.w)) + ((a7.x + a7.y) + (a7.z + a7.w))));
    sde[t] = 1.f / (s + 1e-9f);
  }
  stage(As[0], Bs[0], 0);
  stage(As[1], Bs[1], 1);
  __syncthreads();
  const int NT = 32;
  uint16_t *cA = As[0], *nA = As[1], *fA = As[2];
  uint16_t *cB = Bs[0], *nB = Bs[1], *fB = Bs[2];
  for (int kt = 0; kt < NT - 2; ++kt) {
    stage(fA, fB, kt + 2);
    compute(cA, cB);
    PIPE_WAIT4();  // drain tile kt+1's loads; tile kt+2's stay in flight
    uint16_t* t1 = cA; cA = nA; nA = fA; fA = t1;
    uint16_t* t2 = cB; cB = nB; nB = fB; fB = t2;
  }
  compute(cA, cB);   // tile NT-2
  PIPE_WAIT0();      // drain tile NT-1's loads
  compute(nA, nB);   // tile NT-1
  #pragma unroll
  for (int i = 0; i < 2; ++i) {
    const int fr = f0 + (wave >> 1) * 32 + i * 16 + lq * 4;
    #pragma unroll
    for (int j = 0; j < 2; ++j) {
      const int el = (wave & 1) * 32 + j * 16 + l15;
      const float sc = sde[el];
      uint16_t* dst = Yt + ((size_t)b * 256 + fr) * 1024 + e0 + el;
      #pragma unroll
      for (int reg = 0; reg < 4; ++reg)
        dst[(size_t)reg * 1024] = f2b(acc[i][j][reg] * sc);
    }
  }
}

// ---- GEMM3: out[b][n][f] = relu( DvInv[b,n] * sum_e Hb[n][e]*Yt[f][e] ) ----
// tile 64n x 64f, K=1024 (NT=16). grid (32, 4, 8). same pipeline as gemm2.
__global__ __launch_bounds__(256) void k_gemm3(const uint16_t* __restrict__ Hb,
    const uint16_t* __restrict__ Yt, const float* __restrict__ DvPart,
    float* __restrict__ out) {
  __shared__ __align__(16) uint16_t As[3][64 * 64];
  __shared__ __align__(16) uint16_t Bs[3][64 * 64];
  __shared__ float sdv[64];
  const int n0 = blockIdx.x * 64, f0 = blockIdx.y * 64, b = blockIdx.z;
  const int t = threadIdx.x, lane = t & 63, wave = t >> 6;
  const int l15 = lane & 15, lq = lane >> 4;
  const int rlane = lane >> 3;
  const int srcswz = ((lane & 7) ^ rlane) << 3;
  const uint16_t* Ag = Hb + ((size_t)b * 2048 + n0) * 1024;
  const uint16_t* Bg = Yt + ((size_t)b * 256 + f0) * 1024;
  auto stage = [&](uint16_t* Ad, uint16_t* Bd, int kt) {  // 4 VMEM instrs/wave
    const int k0 = kt * 64;
    #pragma unroll
    for (int i = 0; i < 2; ++i) {
      const int r = wave * 16 + i * 8;
      gload16(Ag + (size_t)(r + rlane) * 1024 + k0 + srcswz, Ad + r * 64);
      gload16(Bg + (size_t)(r + rlane) * 1024 + k0 + srcswz, Bd + r * 64);
    }
  };
  f32x4 acc[2][2] = {};
  auto compute = [&](const uint16_t* Ad, const uint16_t* Bd) {
    #pragma unroll
    for (int h = 0; h < 2; ++h) {
      bf16x8 af[2], bf[2];
      #pragma unroll
      for (int i = 0; i < 2; ++i) {
        const int r = (wave >> 1) * 32 + i * 16 + l15;
        af[i] = *(const bf16x8*)(Ad + r * 64 + ((((h << 2) | lq) ^ (r & 7)) << 3));
      }
      #pragma unroll
      for (int j = 0; j < 2; ++j) {
        const int r = (wave & 1) * 32 + j * 16 + l15;
        bf[j] = *(const bf16x8*)(Bd + r * 64 + ((((h << 2) | lq) ^ (r & 7)) << 3));
      }
      #pragma unroll
      for (int i = 0; i < 2; ++i)
        #pragma unroll
        for (int j = 0; j < 2; ++j)
          acc[i][j] = mfma16(af[i], bf[j], acc[i][j]);
    }
  };
  if (t < 64) {
    const float* p = DvPart + ((size_t)b * 2048 + n0 + t) * 16;
    float4 a0 = *(const float4*)(p + 0),  a1 = *(const float4*)(p + 4);
    float4 a2 = *(const float4*)(p + 8),  a3 = *(const float4*)(p + 12);
    float s = (((a0.x + a0.y) + (a0.z + a0.w)) + ((a1.x + a1.y) + (a1.z + a1.w)))
            + (((a2.x + a2.y) + (a2.z + a2.w)) + ((a3.x + a3.y) + (a3.z + a3.w)));
    sdv[t] = 1.f / (s + 1e-9f);
  }
  stage(As[0], Bs[0], 0);
  stage(As[1], Bs[1], 1);
  __syncthreads();
  const int NT = 16;
  uint16_t *cA = As[0], *nA = As[1], *fA = As[2];
  uint16_t *cB = Bs[0], *nB = Bs[1], *fB = Bs[2];
  for (int kt = 0; kt < NT - 2; ++kt) {
    stage(fA, fB, kt + 2);
    compute(cA, cB);
    PIPE_WAIT4();
    uint16_t* t1 = cA; cA = nA; nA = fA; fA = t1;
    uint16_t* t2 = cB; cB = nB; nB = fB; fB = t2;
  }
  compute(cA, cB);   // tile NT-2
  PIPE_WAIT0();
  compute(nA, nB);   // tile NT-1
  #pragma unroll
  for (int i = 0; i < 2; ++i) {
    const int nl = (wave >> 1) * 32 + i * 16 + lq * 4;
    #pragma unroll
    for (int reg = 0; reg < 4; ++reg) {
      const int row = n0 + nl + reg;
      const float sc = sdv[nl + reg];
      #pragma unroll
      for (int j = 0; j < 2; ++j) {
        const int col = f0 + (wave & 1) * 32 + j * 16 + l15;
        const float v = acc[i][j][reg] * sc;
        out[((size_t)b * 2048 + row) * 256 + col] = v > 0.f ? v : 0.f;
      }
    }
  }
}

extern "C" void kernel_launch(void* const* d_in, const int* in_sizes, int n_in,
                              void* d_out, int out_size, void* d_ws, size_t ws_size,
                              hipStream_t stream) {
  (void)in_sizes; (void)n_in; (void)out_size;
  const float* x = (const float*)d_in[0];   // [8,2048,256]
  const float* H = (const float*)d_in[1];   // [8,2048,1024]
  const float* W = (const float*)d_in[2];   // [256,256]
  float* out = (float*)d_out;               // [8,2048,256]

  // workspace layout (bytes):
  //   Hbt    bf16 [8,1024,2048] : 0        .. 33554432
  //   Hb     bf16 [8,2048,1024] : 33554432 .. 67108864
  //   XWt    bf16 [8,256,2048]  : 67108864 .. 75497472
  //   Yt     bf16 [8,256,1024]  : 75497472 .. 79691776
  //   DvPart f32  [8,2048,16]   : 79691776 .. 80740352
  //   DePart f32  [8,1024,32]   : 80740352 .. 81788928
  //   Wt     bf16 [256,256]     : 81788928 .. 81920000
  if (ws_size < 81920000) return;
  char* ws = (char*)d_ws;
  uint16_t* Hbt    = (uint16_t*)(ws);
  uint16_t* Hb     = (uint16_t*)(ws + 33554432);
  uint16_t* XWt    = (uint16_t*)(ws + 67108864);
  uint16_t* Yt     = (uint16_t*)(ws + 75497472);
  float*    DvPart = (float*)(ws + 79691776);
  float*    DePart = (float*)(ws + 80740352);
  uint16_t* Wt     = (uint16_t*)(ws + 81788928);

  k_prep_w<<<dim3(4, 4),     256, 0, stream>>>(W, Wt);
  k_phase1<<<dim3(4608),     256, 0, stream>>>(H, x, Wt, Hbt, Hb, DvPart, DePart, XWt);
  k_gemm2 <<<dim3(16, 4, 8), 256, 0, stream>>>(Hbt, XWt, DePart, Yt);
  k_gemm3 <<<dim3(32, 4, 8), 256, 0, stream>>>(Hb, Yt, DvPart, out);
}